// Round 2
// baseline (1450.856 us; speedup 1.0000x reference)
//
#include <hip/hip_runtime.h>
#include <math.h>

// ---------------- problem constants ----------------
#define NN 50000      // nodes
#define MM 12         // neighbors
#define NM 600000     // edges = NN*MM
#define OF 92         // orig node features
#define FF 64         // node feature dim
#define EE 41         // edge feature dim
#define ES 48         // padded edge stride (bf16), cols 41..47 = 0
#define ZZ 169        // 2*FF + EE
#define EFO 128
#define ECO 192
#define RPB 96        // rows (edges) per block = 8 nodes * 12
#define NPB 8         // nodes per block
#define NBLK 6250     // NN / NPB
#define KP 200        // padded K stride (bf16 elements) in LDS
#define KSTEPS 6      // 6 * 32 = 192 >= 169
#define MT 6          // M-tiles per block (96/16)
#define NSLICE 64     // stats accumulator replication (atomic de-contention)
#define PSTRIDE 1024  // floats per slice

// ---- ZtZ stats path ----
#define ZTP 104       // Zt row stride (bf16 elems); 104*2B=208B -> 2-way-max banks
#define NPR 66        // upper-tri 16x16 tile pairs of 11x11

#define ZTZ_PI {0,0,0,0,0,0,0,0,0,0,0, 1,1,1,1,1,1,1,1,1,1, 2,2,2,2,2,2,2,2,2, \
                3,3,3,3,3,3,3,3, 4,4,4,4,4,4,4, 5,5,5,5,5,5, 6,6,6,6,6, 7,7,7,7, 8,8,8, 9,9, 10}
#define ZTZ_PJ {0,1,2,3,4,5,6,7,8,9,10, 1,2,3,4,5,6,7,8,9,10, 2,3,4,5,6,7,8,9,10, \
                3,4,5,6,7,8,9,10, 4,5,6,7,8,9,10, 5,6,7,8,9,10, 6,7,8,9,10, 7,8,9,10, 8,9,10, 9,10, 10}

typedef __bf16 bf16x8 __attribute__((ext_vector_type(8)));
typedef float  f32x4  __attribute__((ext_vector_type(4)));

__device__ __forceinline__ float lrelu(float x){ return fmaxf(x, 0.01f*x); }
__device__ __forceinline__ float sigm(float x){ return __builtin_amdgcn_rcpf(1.f+__expf(-x)); }
__device__ __forceinline__ float softpl(float x){ return fmaxf(x,0.f) + __logf(1.f+__expf(-fabsf(x))); }
__device__ __forceinline__ unsigned short f2bf(float f){
    __bf16 h = (__bf16)f;
    return __builtin_bit_cast(unsigned short, h);
}
__device__ __forceinline__ float b2f(unsigned short u){
    unsigned int b = ((unsigned int)u) << 16;
    return __builtin_bit_cast(float, b);
}
__device__ __forceinline__ unsigned short f2h(float f){
    _Float16 h = (_Float16)f;
    return __builtin_bit_cast(unsigned short, h);
}
__device__ __forceinline__ float h2f(unsigned short u){
    return (float)__builtin_bit_cast(_Float16, u);
}

// ---------------- weight packing into B-fragment layout (bf16) ----------------
__global__ __launch_bounds__(256) void pack_w(const float* __restrict__ Wn,
    const float* __restrict__ We, const float* __restrict__ Wd,
    const float* __restrict__ Wc, unsigned short* __restrict__ dst)
{
    int idx = blockIdx.x*256 + threadIdx.x;
    if (idx >= 4*49152) return;
    int j    = idx & 7;
    int lane = (idx >> 3) & 63;
    int ntks = (idx >> 9) % 96;         // ks*16 + nt
    int L    = idx / 49152;
    int nt = ntks & 15, ks = ntks >> 4;
    int k   = ks*32 + (lane>>4)*8 + j;
    int col = nt*16 + (lane&15);
    float v = 0.f;
    if (k < ZZ) {
        if (L < 3) {
            if (col < 128)                       v = Wn[((size_t)L*ZZ + k)*128 + col];
            else if (col >= EFO && col < EFO+EE) v = We[((size_t)L*ZZ + k)*82 + (col-EFO)];
            else if (col >= ECO && col < ECO+EE) v = We[((size_t)L*ZZ + k)*82 + 41 + (col-ECO)];
        } else {
            if (col < 128) v = Wd[(size_t)k*128 + col];
            else           v = Wc[(size_t)k*128 + (col-128)];
        }
    }
    dst[idx] = f2bf(v);
}

// ---------------- distance ----------------
__global__ __launch_bounds__(256) void k_dist(const float* __restrict__ off,
    const float* __restrict__ apos, const float* __restrict__ cells,
    const int* __restrict__ eidx, float* __restrict__ distb)
{
    int idx = blockIdx.x*256 + threadIdx.x;
    if (idx >= NM) return;
    int n = idx / MM;
    const float* o  = off + (size_t)idx*3;
    const float* cl = cells + (size_t)n*9;
    int n2 = eidx[idx];
    float o0=o[0], o1=o[1], o2=o[2];
    float dd = 1e-12f;
    #pragma unroll
    for (int j=0;j<3;j++){
        float oc = o0*cl[0*3+j] + o1*cl[1*3+j] + o2*cl[2*3+j];
        float d = apos[(size_t)n2*3+j] + oc - apos[(size_t)n*3+j];
        dd += d*d;
    }
    distb[idx] = sqrtf(dd);
}

// ---------------- edge convert: fp32 [NM][41] -> bf16 [NM][48] (pad 0) ----------------
__global__ __launch_bounds__(256) void k_cvt(const float* __restrict__ src,
    unsigned short* __restrict__ e)
{
    int idx = blockIdx.x*256 + threadIdx.x;
    if (idx >= NM*ES) return;
    int gr = idx / ES;
    int c  = idx - gr*ES;
    e[idx] = (c < EE) ? f2bf(src[(size_t)gr*EE + c]) : (unsigned short)0;
}

// ---------------- embedding: node0 = bf16(node_fea @ W_emb + b_emb) ----------------
__global__ __launch_bounds__(256) void k_emb(const float* __restrict__ nf,
    const float* __restrict__ W, const float* __restrict__ b,
    unsigned short* __restrict__ node0)
{
    int idx = blockIdx.x*256 + threadIdx.x;
    if (idx >= NN*FF) return;
    int n = idx >> 6, c = idx & 63;
    float s = b[c];
    for (int k=0;k<OF;k++) s = fmaf(nf[(size_t)n*OF+k], W[k*FF+c], s);
    node0[idx] = f2bf(s);
}

// ---------------- slice reduce: st[lo..hi) = sum over NSLICE slices; clear slices ----------------
__global__ __launch_bounds__(256) void k_red(float* __restrict__ P,
    float* __restrict__ dst, int lo, int hi)
{
    for (int c = lo + threadIdx.x; c < hi; c += 256) {
        float s = 0.f;
        #pragma unroll 8
        for (int sl = 0; sl < NSLICE; ++sl) s += P[sl*PSTRIDE + c];
        dst[c] = s;
        #pragma unroll 8
        for (int sl = 0; sl < NSLICE; ++sl) P[sl*PSTRIDE + c] = 0.f;
    }
}

// ================= ZtZ stats path =================
// Stage Z TRANSPOSED: Zt[col][row], 176 cols (col 169 = 1.0 constant), 96 rows.
__device__ __forceinline__ void stage_zt(unsigned short* __restrict__ Zt,
    const unsigned short* __restrict__ node_src, const unsigned short* __restrict__ edge_src,
    const int* __restrict__ eidx, int n0, int tid)
{
    const int gr0 = n0 * MM;
    // self node: cols 0..63
    #pragma unroll
    for (int it=0; it<3; ++it){
        int i = it*256 + tid;
        int r = i >> 3, ch = i & 7;
        int n = n0 + r/MM;
        uint4 v = *(const uint4*)(node_src + (size_t)n*FF + ch*8);
        unsigned short s[8]; *(uint4*)s = v;
        #pragma unroll
        for (int j=0;j<8;j++) Zt[(ch*8+j)*ZTP + r] = s[j];
    }
    // neighbor node (gather): cols 64..127
    #pragma unroll
    for (int it=0; it<3; ++it){
        int i = it*256 + tid;
        int r = i >> 3, ch = i & 7;
        int n2 = eidx[gr0 + r];
        uint4 v = *(const uint4*)(node_src + (size_t)n2*FF + ch*8);
        unsigned short s[8]; *(uint4*)s = v;
        #pragma unroll
        for (int j=0;j<8;j++) Zt[(64+ch*8+j)*ZTP + r] = s[j];
    }
    // edge features: cols 128..175 (ebuf cols 0..47; col 41 -> global 169 forced to 1.0)
    #pragma unroll
    for (int it=0; it<3; ++it){
        int i = it*256 + tid;
        int r = i >> 3, ch = i & 7;
        if (ch < 6) {
            uint4 v = *(const uint4*)(edge_src + (size_t)(gr0+r)*ES + ch*8);
            unsigned short s[8]; *(uint4*)s = v;
            #pragma unroll
            for (int j=0;j<8;j++){
                int c = ch*8 + j;
                unsigned short val = (c == EE) ? (unsigned short)0x3F80 : s[j]; // ones col
                Zt[(128+c)*ZTP + r] = val;
            }
        }
    }
}

template<int W>
__device__ __forceinline__ void ztz_mfma(const unsigned short* __restrict__ Zt,
    int lane, f32x4 (&acc)[17])
{
    constexpr int PI[NPR] = ZTZ_PI;
    constexpr int PJ[NPR] = ZTZ_PJ;
    const int quad = lane >> 4, li = lane & 15;
    #pragma unroll
    for (int ks=0; ks<3; ++ks){
        bf16x8 fr[11];
        #pragma unroll
        for (int t=0;t<11;t++)
            fr[t] = *(const bf16x8*)(Zt + (t*16+li)*ZTP + ks*32 + quad*8);
        #pragma unroll
        for (int p=0;p<17;p++){
            if (W + 4*p < NPR)
                acc[p] = __builtin_amdgcn_mfma_f32_16x16x32_bf16(
                    fr[PI[W+4*p]], fr[PJ[W+4*p]], acc[p], 0, 0, 0);
        }
    }
}

// persistent blocks: each accumulates its tiles' Z^T Z in registers, dumps to own region
__global__ __launch_bounds__(256) void k_ztz(
    const unsigned short* __restrict__ node_src, const unsigned short* __restrict__ edge_src,
    const int* __restrict__ eidx, float* __restrict__ Spart)
{
    __shared__ unsigned short Zt[176*ZTP];
    const int tid = threadIdx.x, w = tid>>6, lane = tid&63;
    f32x4 acc[17];
    #pragma unroll
    for (int p=0;p<17;p++) acc[p] = (f32x4){0.f,0.f,0.f,0.f};

    for (int tb = blockIdx.x; tb < NBLK; tb += gridDim.x){
        stage_zt(Zt, node_src, edge_src, eidx, tb*NPB, tid);
        __syncthreads();
        if      (w==0) ztz_mfma<0>(Zt, lane, acc);
        else if (w==1) ztz_mfma<1>(Zt, lane, acc);
        else if (w==2) ztz_mfma<2>(Zt, lane, acc);
        else           ztz_mfma<3>(Zt, lane, acc);
        __syncthreads();
    }
    float* R = Spart + (size_t)blockIdx.x * (NPR*256);
    #pragma unroll
    for (int p=0;p<17;p++){
        int idx = w + 4*p;
        if (idx < NPR){
            #pragma unroll
            for (int r=0;r<4;r++)
                R[idx*256 + r*64 + lane] = acc[p][r];
        }
    }
}

// fold regions + expand tile fragments into full S[176][176] (S pre-zeroed)
__global__ __launch_bounds__(256) void k_sexp(const float* __restrict__ Spart,
    int nreg, float* __restrict__ S)
{
    constexpr int PI[NPR] = ZTZ_PI;
    constexpr int PJ[NPR] = ZTZ_PJ;
    const int p = blockIdx.x >> 3, oct = blockIdx.x & 7;
    const int idx = threadIdx.x;
    float s = 0.f;
    for (int b = oct; b < nreg; b += 8)
        s += Spart[(size_t)b*(NPR*256) + p*256 + idx];
    int r  = idx >> 6, ln = idx & 63;
    int row = PI[p]*16 + ((ln>>4)<<2) + r;
    int col = PJ[p]*16 + (ln&15);
    atomicAdd(&S[row*176 + col], s);
    if (PI[p] != PJ[p]) atomicAdd(&S[col*176 + row], s);
}

// per output column c: preS[c] = sumz^T w, preQ[c] = w^T S w  (w rounded thru bf16)
__global__ __launch_bounds__(256) void k_bnstat(const float* __restrict__ S,
    const float* __restrict__ Wa, const float* __restrict__ Wb, int mode,
    float* __restrict__ outS, float* __restrict__ outQ)
{
    __shared__ float wl[176];
    __shared__ float red[256];
    const int c = blockIdx.x, tid = threadIdx.x;
    float wv = 0.f;
    if (tid < ZZ){
        float raw = 0.f;
        if (mode == 0){
            if (c < 128)                    raw = Wa[tid*128 + c];
            else if (c < 128+EE)            raw = Wb[tid*82 + (c-128)];
            else if (c >= ECO && c < ECO+EE) raw = Wb[tid*82 + 41 + (c-ECO)];
        } else {
            raw = (c < 128) ? Wa[tid*128 + c] : Wb[tid*128 + (c-128)];
        }
        wv = b2f(f2bf(raw));
    }
    if (tid < 176) wl[tid] = wv;
    __syncthreads();
    float u = 0.f;
    if (tid < 176){
        for (int k2=0; k2<ZZ; ++k2)
            u = fmaf(S[k2*176 + tid], wl[k2], u);
    }
    float qp = wv * u;
    float mp = (tid < ZZ) ? wv * S[tid*176 + 169] : 0.f;
    red[tid] = qp; __syncthreads();
    for (int s=128; s>0; s>>=1){ if (tid<s) red[tid] += red[tid+s]; __syncthreads(); }
    float q = red[0]; __syncthreads();
    red[tid] = mp; __syncthreads();
    for (int s=128; s>0; s>>=1){ if (tid<s) red[tid] += red[tid+s]; __syncthreads(); }
    if (tid == 0){ outS[c] = red[0]; outQ[c] = q; }
}

// ---------------- z staging into LDS: bf16 [96][KP], three branch-free sections ----------------
__device__ __forceinline__ void stage_z(unsigned short* __restrict__ Zl,
    const unsigned short* __restrict__ node_src, const unsigned short* __restrict__ edge_src,
    const int* __restrict__ eidx, int n0, int tid)
{
    const int gr0 = n0 * MM;
    #pragma unroll
    for (int it=0; it<3; ++it){
        int i = it*256 + tid;
        int row = i >> 3, ch = i & 7;
        int n = n0 + row/MM;
        uint4 v = *(const uint4*)(node_src + (size_t)n*FF + ch*8);
        *(uint4*)(Zl + row*KP + ch*8) = v;
    }
    #pragma unroll
    for (int it=0; it<3; ++it){
        int i = it*256 + tid;
        int row = i >> 3, ch = i & 7;
        int n2 = eidx[gr0 + row];
        uint4 v = *(const uint4*)(node_src + (size_t)n2*FF + ch*8);
        *(uint4*)(Zl + row*KP + 64 + ch*8) = v;
    }
    #pragma unroll
    for (int it=0; it<3; ++it){
        int i = it*256 + tid;
        int row = i >> 3, ch = i & 7;
        uint4 v = make_uint4(0u,0u,0u,0u);
        if (ch < 6) v = *(const uint4*)(edge_src + (size_t)(gr0+row)*ES + ch*8);
        *(uint4*)(Zl + row*KP + 128 + ch*8) = v;
    }
}

// ---------------- MFMA core: 6 M-tiles x 4 col-group tiles per wave ----------------
__device__ __forceinline__ void mfma_core(const unsigned short* __restrict__ Zl,
    const unsigned short* __restrict__ Wpk, int w, int lane, f32x4 (&acc)[MT][4])
{
    const int quad = lane >> 4, li = lane & 15;
    #pragma unroll
    for (int mt=0;mt<MT;mt++)
        #pragma unroll
        for (int t=0;t<4;t++) acc[mt][t] = (f32x4){0.f,0.f,0.f,0.f};

    #pragma unroll 2
    for (int ks=0; ks<KSTEPS; ++ks) {
        bf16x8 bfr[4];
        #pragma unroll
        for (int t=0;t<4;t++){
            int nt = w + 4*t;
            bfr[t] = *(const bf16x8*)(Wpk + (((ks*16 + nt)*64 + lane) << 3));
        }
        bf16x8 afr[MT];
        #pragma unroll
        for (int mt=0;mt<MT;mt++){
            int row = mt*16 + li;
            afr[mt] = *(const bf16x8*)(Zl + row*KP + ks*32 + quad*8);
        }
        #pragma unroll
        for (int mt=0;mt<MT;mt++)
            #pragma unroll
            for (int t=0;t<4;t++)
                acc[mt][t] = __builtin_amdgcn_mfma_f32_16x16x32_bf16(afr[mt], bfr[t], acc[mt][t], 0, 0, 0);
    }
}

// ---------------- stats epilogue (sliced accumulators: sumv at Ps[0], sumq at Ps[256]) ----------------
__device__ __forceinline__ void stats_epi(const f32x4 (&acc)[MT][4], int w, int lane,
    float* __restrict__ Ps)
{
    const int quad = lane>>4, li = lane&15;
    #pragma unroll
    for (int t=0;t<4;t++){
        float s=0.f, q=0.f;
        #pragma unroll
        for (int mt=0;mt<MT;mt++)
            #pragma unroll
            for (int r=0;r<4;r++){ float v = acc[mt][t][r]; s+=v; q = fmaf(v,v,q); }
        s += __shfl_xor(s,16); s += __shfl_xor(s,32);
        q += __shfl_xor(q,16); q += __shfl_xor(q,32);
        if (quad == 0) {
            int col = t*64 + w*16 + li;
            atomicAdd(&Ps[col], s);
            atomicAdd(&Ps[256+col], q);
        }
    }
}

// ---------------- GEMM + stats (fallback: no Y spill) ----------------
__global__ __launch_bounds__(256) void k_stats(
    const unsigned short* __restrict__ node_src, const unsigned short* __restrict__ edge_src,
    const int* __restrict__ eidx, const unsigned short* __restrict__ Wpk,
    float* __restrict__ Pst)
{
    __shared__ unsigned short Zl[RPB*KP];
    const int tid = threadIdx.x, w = tid>>6, lane = tid&63;
    const int n0 = blockIdx.x * NPB;
    stage_z(Zl, node_src, edge_src, eidx, n0, tid);
    __syncthreads();
    f32x4 acc[MT][4];
    mfma_core(Zl, Wpk, w, lane, acc);
    float* Ps = Pst + (size_t)(blockIdx.x & (NSLICE-1))*PSTRIDE;
    stats_epi(acc, w, lane, Ps);
}

// ---------------- GEMM + stats + Y spill (fp16, C-fragment tile layout) ----------------
__global__ __launch_bounds__(256) void k_gemm(
    const unsigned short* __restrict__ node_src, const unsigned short* __restrict__ edge_src,
    const int* __restrict__ eidx, const unsigned short* __restrict__ Wpk,
    float* __restrict__ Pst, ushort4* __restrict__ Y)
{
    __shared__ unsigned short Zl[RPB*KP];
    const int tid = threadIdx.x, w = tid>>6, lane = tid&63;
    const int b = blockIdx.x;
    const int n0 = b * NPB;
    stage_z(Zl, node_src, edge_src, eidx, n0, tid);
    __syncthreads();
    f32x4 acc[MT][4];
    mfma_core(Zl, Wpk, w, lane, acc);
    #pragma unroll
    for (int mt=0;mt<MT;mt++)
        #pragma unroll
        for (int t=0;t<4;t++){
            ushort4 h;
            h.x = f2h(acc[mt][t][0]); h.y = f2h(acc[mt][t][1]);
            h.z = f2h(acc[mt][t][2]); h.w = f2h(acc[mt][t][3]);
            Y[((size_t)b*96 + mt*16 + t*4 + w)*64 + lane] = h;
        }
    float* Ps = Pst + (size_t)(blockIdx.x & (NSLICE-1))*PSTRIDE;
    stats_epi(acc, w, lane, Ps);
}

// ---------------- apply epilogue core (shared by both apply variants) ----------------
__device__ __forceinline__ void apply_epi(float (&vals)[4], int mt,
    int quad, int cg, bool ce_ok, const float sc[4], const float bi[4],
    int r, int gr0, float* __restrict__ gL, unsigned short* __restrict__ gbuf,
    float& pg, float& pq)
{
    int row = mt*16 + quad*4 + r;
    float nf = fmaf(vals[0], sc[0], bi[0]);
    float nc = fmaf(vals[1], sc[1], bi[1]);
    gL[row*68 + cg] = sigm(nf) * lrelu(nc);
    if (ce_ok) {
        float ef = fmaf(vals[2], sc[2], bi[2]);
        float ec = fmaf(vals[3], sc[3], bi[3]);
        float gv = sigm(ef)*lrelu(ec);
        gbuf[(size_t)(gr0+row)*ES + cg] = f2bf(gv);
        pg += gv; pq = fmaf(gv,gv,pq);
    }
}

__device__ __forceinline__ void apply_tail(float pg, float pq, int tid, int quad,
    int cg, bool ce_ok, int n0, const float* __restrict__ gL,
    float* __restrict__ aggr, float* __restrict__ aS, float* __restrict__ aQ,
    float* __restrict__ gS, float* __restrict__ gQ)
{
    pg += __shfl_xor(pg,16); pg += __shfl_xor(pg,32);
    pq += __shfl_xor(pq,16); pq += __shfl_xor(pq,32);
    if (quad==0 && ce_ok){ atomicAdd(&gS[cg], pg); atomicAdd(&gQ[cg], pq); }
    __syncthreads();
    if (tid < 64) {
        float sAcc=0.f, sQq=0.f;
        #pragma unroll
        for (int nl=0; nl<NPB; nl++){
            float vsum = 0.f;
            #pragma unroll
            for (int jj=0;jj<MM;jj++) vsum += gL[(nl*MM+jj)*68 + tid];
            aggr[(size_t)(n0+nl)*64 + tid] = vsum;
            sAcc += vsum; sQq = fmaf(vsum,vsum,sQq);
        }
        atomicAdd(&aS[tid], sAcc);
        atomicAdd(&aQ[tid], sQq);
    }
}

// ---------------- apply pass, Y path (epilogue-only) ----------------
__global__ __launch_bounds__(256) void k_apply_y(
    const ushort4* __restrict__ Y,
    const float* __restrict__ preS, const float* __restrict__ preQ,
    float* __restrict__ aggr, unsigned short* __restrict__ gbuf,
    float* __restrict__ Pst)
{
    __shared__ float gL[RPB*68];
    const int tid = threadIdx.x, w = tid>>6, lane = tid&63;
    const int quad = lane>>4, li = lane&15;
    const int b = blockIdx.x;
    const int n0 = b * NPB;
    const int gr0 = n0 * MM;
    const int cg = w*16 + li;

    float sc[4], bi[4];
    #pragma unroll
    for (int t=0;t<4;t++){
        int col = t*64 + cg;
        float mm = preS[col]*(1.f/(float)NM);
        float vv = preQ[col]*(1.f/(float)NM) - mm*mm;
        float is = rsqrtf(vv + 1e-5f);
        sc[t] = is; bi[t] = -mm*is;
    }

    float pg = 0.f, pq = 0.f;
    const bool ce_ok = cg < EE;
    #pragma unroll
    for (int mt=0;mt<MT;mt++){
        unsigned short a[4][4];
        #pragma unroll
        for (int t=0;t<4;t++)
            *(ushort4*)a[t] = Y[((size_t)b*96 + mt*16 + t*4 + w)*64 + lane];
        #pragma unroll
        for (int r=0;r<4;r++){
            float vals[4] = {h2f(a[0][r]), h2f(a[1][r]), h2f(a[2][r]), h2f(a[3][r])};
            apply_epi(vals, mt, quad, cg, ce_ok, sc, bi, r, gr0, gL, gbuf, pg, pq);
        }
    }
    float* Ps = Pst + (size_t)(b & (NSLICE-1))*PSTRIDE;
    apply_tail(pg, pq, tid, quad, cg, ce_ok, n0, gL, aggr, Ps+512, Ps+576, Ps+640, Ps+704);
}

// ---------------- apply pass, fallback (recompute GEMM) ----------------
__global__ __launch_bounds__(256) void k_apply_re(
    const unsigned short* __restrict__ node_src, const unsigned short* __restrict__ edge_src,
    const int* __restrict__ eidx, const unsigned short* __restrict__ Wpk,
    const float* __restrict__ preS, const float* __restrict__ preQ,
    float* __restrict__ aggr, unsigned short* __restrict__ gbuf,
    float* __restrict__ Pst)
{
    __shared__ __align__(16) char smem[RPB*KP*2];   // Zl; gL [96][68] aliases after sync
    unsigned short* Zl = (unsigned short*)smem;
    float* gL = (float*)smem;
    const int tid = threadIdx.x, w = tid>>6, lane = tid&63;
    const int quad = lane>>4, li = lane&15;
    const int n0 = blockIdx.x * NPB;
    const int gr0 = n0 * MM;
    stage_z(Zl, node_src, edge_src, eidx, n0, tid);
    __syncthreads();
    f32x4 acc[MT][4];
    mfma_core(Zl, Wpk, w, lane, acc);
    __syncthreads();                 // Zl dead -> gL may alias

    const int cg = w*16 + li;
    float sc[4], bi[4];
    #pragma unroll
    for (int t=0;t<4;t++){
        int col = t*64 + cg;
        float mm = preS[col]*(1.f/(float)NM);
        float vv = preQ[col]*(1.f/(float)NM) - mm*mm;
        float is = rsqrtf(vv + 1e-5f);
        sc[t] = is; bi[t] = -mm*is;
    }
    float pg = 0.f, pq = 0.f;
    const bool ce_ok = cg < EE;
    #pragma unroll
    for (int mt=0;mt<MT;mt++)
        #pragma unroll
        for (int r=0;r<4;r++){
            float vals[4] = {acc[mt][0][r], acc[mt][1][r], acc[mt][2][r], acc[mt][3][r]};
            apply_epi(vals, mt, quad, cg, ce_ok, sc, bi, r, gr0, gL, gbuf, pg, pq);
        }
    float* Ps = Pst + (size_t)(blockIdx.x & (NSLICE-1))*PSTRIDE;
    apply_tail(pg, pq, tid, quad, cg, ce_ok, n0, gL, aggr, Ps+512, Ps+576, Ps+640, Ps+704);
}

// ---------------- residual updates (scale/bias inline from raw sums) ----------------
__global__ __launch_bounds__(256) void k_upd_node(const unsigned short* __restrict__ cur,
    const float* __restrict__ aggr, const float* __restrict__ aS,
    const float* __restrict__ aQ, unsigned short* __restrict__ nxt)
{
    int idx = blockIdx.x*256 + threadIdx.x;
    if (idx >= NN*8) return;
    int n = idx >> 3, ch = idx & 7;
    int base = n*64 + ch*8;
    float4 a0 = *(const float4*)(aggr + base);
    float4 a1 = *(const float4*)(aggr + base + 4);
    uint4 cu = *(const uint4*)(cur + base);
    unsigned short cs[8]; *(uint4*)cs = cu;
    float av[8] = {a0.x,a0.y,a0.z,a0.w,a1.x,a1.y,a1.z,a1.w};
    unsigned short os[8];
    #pragma unroll
    for (int j=0;j<8;j++){
        int c = ch*8+j;
        float mm = aS[c]*(1.f/(float)NN);
        float vv = aQ[c]*(1.f/(float)NN) - mm*mm;
        float is = rsqrtf(vv + 1e-5f);
        float v = (av[j] - mm) * is;
        os[j] = f2bf(lrelu(b2f(cs[j]) + v));
    }
    *(uint4*)(nxt + base) = *(uint4*)os;
}

__global__ __launch_bounds__(256) void k_upd_edge(unsigned short* __restrict__ e,
    const unsigned short* __restrict__ g, const float* __restrict__ gS,
    const float* __restrict__ gQ)
{
    int idx = blockIdx.x*256 + threadIdx.x;
    if (idx >= NM*6) return;
    int gr = idx / 6, ch = idx - gr*6;
    size_t base = (size_t)gr*ES + ch*8;
    uint4 eu = *(const uint4*)(e + base);
    uint4 gu = *(const uint4*)(g + base);
    unsigned short es8[8], gs8[8], os[8];
    *(uint4*)es8 = eu; *(uint4*)gs8 = gu;
    #pragma unroll
    for (int j=0;j<8;j++){
        int c = ch*8+j;
        if (c < EE) {
            float mm = gS[c]*(1.f/(float)NM);
            float vv = gQ[c]*(1.f/(float)NM) - mm*mm;
            float is = rsqrtf(vv + 1e-5f);
            float v = (b2f(gs8[j]) - mm) * is;
            os[j] = f2bf(lrelu(b2f(es8[j]) + v));
        } else {
            os[j] = es8[j];
        }
    }
    *(uint4*)(e + base) = *(uint4*)os;
}

// ---------------- final-head epilogue core ----------------
__device__ __forceinline__ void final_epi(const float vals[4], int mt, int r,
    int quad, int w, int liq, bool wr, const float sc[4], const float bi[4],
    int gr0, const float* __restrict__ distb,
    float* __restrict__ bufD, float* __restrict__ bufC)
{
    int row = mt*16 + quad*4 + r;
    float dv = distb[gr0 + row];
    float pd = softpl(fmaf(vals[0],sc[0],bi[0]) + dv)
             + softpl(fmaf(vals[1],sc[1],bi[1]) + dv);
    float pc = softpl(fmaf(vals[2],sc[2],bi[2]))
             + softpl(fmaf(vals[3],sc[3],bi[3]));
    pd += __shfl_xor(pd,1); pd += __shfl_xor(pd,2);
    pc += __shfl_xor(pc,1); pc += __shfl_xor(pc,2);
    if (wr) {
        bufD[row*17 + w*4 + liq] = pd;
        bufC[row*17 + w*4 + liq] = pc;
    }
}

__device__ __forceinline__ void final_tail(int tid, int gr0,
    const float* __restrict__ bufD, const float* __restrict__ bufC,
    float* __restrict__ out)
{
    __syncthreads();
    if (tid < 2*RPB) {
        int h = tid >= RPB;
        int row = tid - (h ? RPB : 0);
        const float* buf = h ? bufC : bufD;
        float s = 0.f;
        #pragma unroll
        for (int t=0;t<16;t++) s += buf[row*17+t];
        size_t gr = gr0 + row;
        out[gr*2 + h] = h ? s * (1.f/128.f) * (1.f/(float)NN) : s * (1.f/128.f);
    }
}

// ---------------- final heads, Y path ----------------
__global__ __launch_bounds__(256) void k_final_y(
    const ushort4* __restrict__ Y,
    const float* __restrict__ fS, const float* __restrict__ fQ,
    const float* __restrict__ distb, float* __restrict__ out)
{
    __shared__ float bufD[RPB*17];
    __shared__ float bufC[RPB*17];
    const int tid = threadIdx.x, w = tid>>6, lane = tid&63;
    const int quad = lane>>4, li = lane&15;
    const int b = blockIdx.x;
    const int gr0 = b * NPB * MM;
    const int cg = w*16 + li;

    float sc[4], bi[4];
    #pragma unroll
    for (int t=0;t<4;t++){
        int col = t*64 + cg;
        float mm = fS[col]*(1.f/(float)NM);
        float vv = fQ[col]*(1.f/(float)NM) - mm*mm;
        float is = rsqrtf(vv + 1e-5f);
        sc[t] = is; bi[t] = -mm*is;
    }
    const int liq = li >> 2;
    const bool wr = (li & 3) == 0;
    #pragma unroll
    for (int mt=0;mt<MT;mt++){
        unsigned short a[4][4];
        #pragma unroll
        for (int t=0;t<4;t++)
            *(ushort4*)a[t] = Y[((size_t)b*96 + mt*16 + t*4 + w)*64 + lane];
        #pragma unroll
        for (int r=0;r<4;r++){
            float vals[4] = {h2f(a[0][r]), h2f(a[1][r]), h2f(a[2][r]), h2f(a[3][r])};
            final_epi(vals, mt, r, quad, w, liq, wr, sc, bi, gr0, distb, bufD, bufC);
        }
    }
    final_tail(tid, gr0, bufD, bufC, out);
}

// ---------------- final heads, fallback (recompute GEMM) ----------------
__global__ __launch_bounds__(256) void k_final_re(
    const unsigned short* __restrict__ node_src, const unsigned short* __restrict__ edge_src,
    const int* __restrict__ eidx, const unsigned short* __restrict__ Wpk,
    const float* __restrict__ fS, const float* __restrict__ fQ,
    const float* __restrict__ distb, float* __restrict__ out)
{
    __shared__ __align__(16) char smem[RPB*KP*2];   // Zl; bufD/bufC alias after sync
    unsigned short* Zl = (unsigned short*)smem;
    float* bufD = (float*)smem;                     // [96][17]
    float* bufC = (float*)(smem + 8192);
    const int tid = threadIdx.x, w = tid>>6, lane = tid&63;
    const int quad = lane>>4, li = lane&15;
    const int n0 = blockIdx.x * NPB;
    const int gr0 = n0 * MM;
    stage_z(Zl, node_src, edge_src, eidx, n0, tid);
    __syncthreads();
    f32x4 acc[MT][4];
    mfma_core(Zl, Wpk, w, lane, acc);
    __syncthreads();

    const int cg = w*16 + li;
    float sc[4], bi[4];
    #pragma unroll
    for (int t=0;t<4;t++){
        int col = t*64 + cg;
        float mm = fS[col]*(1.f/(float)NM);
        float vv = fQ[col]*(1.f/(float)NM) - mm*mm;
        float is = rsqrtf(vv + 1e-5f);
        sc[t] = is; bi[t] = -mm*is;
    }
    const int liq = li >> 2;
    const bool wr = (li & 3) == 0;
    #pragma unroll
    for (int mt=0;mt<MT;mt++)
        #pragma unroll
        for (int r=0;r<4;r++){
            float vals[4] = {acc[mt][0][r], acc[mt][1][r], acc[mt][2][r], acc[mt][3][r]};
            final_epi(vals, mt, r, quad, w, liq, wr, sc, bi, gr0, distb, bufD, bufC);
        }
    final_tail(tid, gr0, bufD, bufC, out);
}

// ---------------- launch ----------------
extern "C" void kernel_launch(void* const* d_in, const int* in_sizes, int n_in,
                              void* d_out, int out_size, void* d_ws, size_t ws_size,
                              hipStream_t stream)
{
    const float* node_fea = (const float*)d_in[0];
    const float* edge_in  = (const float*)d_in[1];
    const float* nbr_off  = (const float*)d_in[2];
    const float* apos     = (const float*)d_in[3];
    const float* cells    = (const float*)d_in[4];
    const int*   eidx     = (const int*)  d_in[5];
    const float* W_emb    = (const float*)d_in[6];
    const float* b_emb    = (const float*)d_in[7];
    const float* W_pn     = (const float*)d_in[8];
    const float* W_pe     = (const float*)d_in[10];
    const float* W_dist   = (const float*)d_in[12];
    const float* W_cst    = (const float*)d_in[14];
    float* out = (float*)d_out;
    char* ws = (char*)d_ws;

    size_t o = 0;
    auto alloc = [&](size_t bytes) { char* p = ws + o; o += (bytes + 255) & ~(size_t)255; return p; };
    unsigned short* node0 = (unsigned short*)alloc((size_t)NN*FF*2);
    unsigned short* node1 = (unsigned short*)alloc((size_t)NN*FF*2);
    unsigned short* ebuf  = (unsigned short*)alloc((size_t)NM*ES*2);
    unsigned short* gbuf  = (unsigned short*)alloc((size_t)NM*ES*2);
    float* aggr  = (float*)alloc((size_t)NN*FF*4);
    float* distb = (float*)alloc((size_t)NM*4);
    unsigned short* Wpk = (unsigned short*)alloc((size_t)4*49152*2);
    float* stats = (float*)alloc(4096*4);
    float* Pst   = (float*)alloc((size_t)NSLICE*PSTRIDE*4);   // sliced stats accumulators
    float* Sful  = (float*)alloc((size_t)176*176*4);          // full ZtZ Gram (124KB)

    // Y buffer (fp16 pre-BN GEMM output, 307.2 MB) only if workspace allows
    const size_t YB = (size_t)NBLK*96*64*8;
    const bool useY = (o + YB) <= ws_size;
    ushort4* Ybuf = useY ? (ushort4*)alloc(YB) : (ushort4*)nullptr;

    // ZtZ partials: prefer 512 regions (34.6MB), else 256 (17.3MB), else fallback
    int nbz = 0; float* Spart = nullptr;
    if (!useY) {
        const size_t sp512 = (size_t)512*NPR*256*4;
        const size_t sp256 = (size_t)256*NPR*256*4;
        if (o + sp512 <= ws_size)      { Spart = (float*)alloc(sp512); nbz = 512; }
        else if (o + sp256 <= ws_size) { Spart = (float*)alloc(sp256); nbz = 256; }
    }

    hipMemsetAsync(stats, 0, 4096*sizeof(float), stream);
    hipMemsetAsync(Pst, 0, (size_t)NSLICE*PSTRIDE*sizeof(float), stream);
    pack_w<<<(4*49152+255)/256, 256, 0, stream>>>(W_pn, W_pe, W_dist, W_cst, Wpk);
    k_dist <<<(NM+255)/256,     256, 0, stream>>>(nbr_off, apos, cells, eidx, distb);
    k_cvt  <<<(NM*ES+255)/256,  256, 0, stream>>>(edge_in, ebuf);
    k_emb  <<<(NN*FF+255)/256,  256, 0, stream>>>(node_fea, W_emb, b_emb, node0);

    const unsigned short* ncur = node0;

    for (int l=0;l<3;l++){
        float* st = stats + l*768;
        float* preS = st;       float* preQ = st+256;
        float* aSs  = st+512;   float* aQq  = st+576;
        float* gSs  = st+640;   float* gQq  = st+704;
        const unsigned short* Wl = Wpk + (size_t)l*49152;
        unsigned short* ndst = (l & 1) ? node0 : node1;

        if (useY) {
            k_gemm   <<<NBLK,256,0,stream>>>(ncur, ebuf, eidx, Wl, Pst, Ybuf);
            k_red    <<<1,256,0,stream>>>(Pst, st, 0, 512);
            k_apply_y<<<NBLK,256,0,stream>>>(Ybuf, preS, preQ, aggr, gbuf, Pst);
            k_red    <<<1,256,0,stream>>>(Pst, st, 512, 768);
        } else if (nbz) {
            hipMemsetAsync(Sful, 0, (size_t)176*176*4, stream);
            k_ztz   <<<nbz,256,0,stream>>>(ncur, ebuf, eidx, Spart);
            k_sexp  <<<NPR*8,256,0,stream>>>(Spart, nbz, Sful);
            k_bnstat<<<256,256,0,stream>>>(Sful, W_pn + (size_t)l*ZZ*128,
                                           W_pe + (size_t)l*ZZ*82, 0, preS, preQ);
            k_apply_re<<<NBLK,256,0,stream>>>(ncur, ebuf, eidx, Wl, preS, preQ,
                                              aggr, gbuf, Pst);
            k_red    <<<1,256,0,stream>>>(Pst, st, 512, 768);
        } else {
            k_stats  <<<NBLK,256,0,stream>>>(ncur, ebuf, eidx, Wl, Pst);
            k_red    <<<1,256,0,stream>>>(Pst, st, 0, 512);
            k_apply_re<<<NBLK,256,0,stream>>>(ncur, ebuf, eidx, Wl, preS, preQ,
                                              aggr, gbuf, Pst);
            k_red    <<<1,256,0,stream>>>(Pst, st, 512, 768);
        }
        k_upd_node<<<(NN*8+255)/256,256,0,stream>>>(ncur, aggr, aSs, aQq, ndst);
        k_upd_edge<<<(NM*6+255)/256,256,0,stream>>>(ebuf, gbuf, gSs, gQq);
        ncur = ndst;
    }

    float* fSt = stats + 3*768;
    float* fS = fSt; float* fQ = fSt + 256;
    const unsigned short* Wf = Wpk + (size_t)3*49152;
    if (useY) {
        k_gemm   <<<NBLK,256,0,stream>>>(ncur, ebuf, eidx, Wf, Pst, Ybuf);
        k_red    <<<1,256,0,stream>>>(Pst, fSt, 0, 512);
        k_final_y<<<NBLK,256,0,stream>>>(Ybuf, fS, fQ, distb, out);
    } else if (nbz) {
        hipMemsetAsync(Sful, 0, (size_t)176*176*4, stream);
        k_ztz   <<<nbz,256,0,stream>>>(ncur, ebuf, eidx, Spart);
        k_sexp  <<<NPR*8,256,0,stream>>>(Spart, nbz, Sful);
        k_bnstat<<<256,256,0,stream>>>(Sful, W_dist, W_cst, 1, fS, fQ);
        k_final_re<<<NBLK,256,0,stream>>>(ncur, ebuf, eidx, Wf, fS, fQ, distb, out);
    } else {
        k_stats  <<<NBLK,256,0,stream>>>(ncur, ebuf, eidx, Wf, Pst);
        k_red    <<<1,256,0,stream>>>(Pst, fSt, 0, 512);
        k_final_re<<<NBLK,256,0,stream>>>(ncur, ebuf, eidx, Wf, fS, fQ, distb, out);
    }
}

// Round 3
// 1238.559 us; speedup vs baseline: 1.1714x; 1.1714x over previous
//
#include <hip/hip_runtime.h>
#include <math.h>

// ---------------- problem constants ----------------
#define NN 50000      // nodes
#define MM 12         // neighbors
#define NM 600000     // edges = NN*MM
#define OF 92         // orig node features
#define FF 64         // node feature dim
#define EE 41         // edge feature dim
#define ES 48         // padded edge stride (bf16), cols 41..47 = 0
#define ZZ 169        // 2*FF + EE
#define RPB 96        // rows (edges) per block = 8 nodes * 12
#define NPB 8         // nodes per block
#define NBLK 6250     // NN / NPB
#define KP 200        // padded K stride (bf16 elements) in LDS
#define KSTEPS 6      // 6 * 32 = 192 >= 169
#define MT 6          // M-tiles per block (96/16)
#define NSLICE 64     // stats accumulator replication (atomic de-contention)
#define PSTRIDE 1024  // floats per slice
#define TPB 512       // threads per block in GEMM passes (8 waves)

typedef __bf16 bf16x8 __attribute__((ext_vector_type(8)));
typedef float  f32x4  __attribute__((ext_vector_type(4)));

__device__ __forceinline__ float lrelu(float x){ return fmaxf(x, 0.01f*x); }
__device__ __forceinline__ float sigm(float x){ return __builtin_amdgcn_rcpf(1.f+__expf(-x)); }
__device__ __forceinline__ float softpl(float x){ return fmaxf(x,0.f) + __logf(1.f+__expf(-fabsf(x))); }
__device__ __forceinline__ unsigned short f2bf(float f){
    __bf16 h = (__bf16)f;
    return __builtin_bit_cast(unsigned short, h);
}
__device__ __forceinline__ float b2f(unsigned short u){
    unsigned int b = ((unsigned int)u) << 16;
    return __builtin_bit_cast(float, b);
}

// ---------------- weight packing into B-fragment layout (bf16) ----------------
__global__ __launch_bounds__(256) void pack_w(const float* __restrict__ Wn,
    const float* __restrict__ We, const float* __restrict__ Wd,
    const float* __restrict__ Wc, unsigned short* __restrict__ dst)
{
    int idx = blockIdx.x*256 + threadIdx.x;
    if (idx >= 4*49152) return;
    int j    = idx & 7;
    int lane = (idx >> 3) & 63;
    int ntks = (idx >> 9) % 96;         // ks*16 + nt
    int L    = idx / 49152;
    int nt = ntks & 15, ks = ntks >> 4;
    int k   = ks*32 + (lane>>4)*8 + j;
    int col = nt*16 + (lane&15);
    float v = 0.f;
    if (k < ZZ) {
        if (L < 3) {
            if (col < 128)                       v = Wn[((size_t)L*ZZ + k)*128 + col];
            else if (col >= 128 && col < 128+EE) v = We[((size_t)L*ZZ + k)*82 + (col-128)];
            else if (col >= 192 && col < 192+EE) v = We[((size_t)L*ZZ + k)*82 + 41 + (col-192)];
        } else {
            if (col < 128) v = Wd[(size_t)k*128 + col];
            else           v = Wc[(size_t)k*128 + (col-128)];
        }
    }
    dst[idx] = f2bf(v);
}

// ---------------- distance ----------------
__global__ __launch_bounds__(256) void k_dist(const float* __restrict__ off,
    const float* __restrict__ apos, const float* __restrict__ cells,
    const int* __restrict__ eidx, float* __restrict__ distb)
{
    int idx = blockIdx.x*256 + threadIdx.x;
    if (idx >= NM) return;
    int n = idx / MM;
    const float* o  = off + (size_t)idx*3;
    const float* cl = cells + (size_t)n*9;
    int n2 = eidx[idx];
    float o0=o[0], o1=o[1], o2=o[2];
    float dd = 1e-12f;
    #pragma unroll
    for (int j=0;j<3;j++){
        float oc = o0*cl[0*3+j] + o1*cl[1*3+j] + o2*cl[2*3+j];
        float d = apos[(size_t)n2*3+j] + oc - apos[(size_t)n*3+j];
        dd += d*d;
    }
    distb[idx] = sqrtf(dd);
}

// ---------------- edge convert: fp32 [NM][41] -> bf16 [NM][48] (pad 0) ----------------
__global__ __launch_bounds__(256) void k_cvt(const float* __restrict__ src,
    unsigned short* __restrict__ e)
{
    int idx = blockIdx.x*256 + threadIdx.x;
    if (idx >= NM*ES) return;
    int gr = idx / ES;
    int c  = idx - gr*ES;
    e[idx] = (c < EE) ? f2bf(src[(size_t)gr*EE + c]) : (unsigned short)0;
}

// ---------------- embedding: node0 = bf16(node_fea @ W_emb + b_emb) ----------------
__global__ __launch_bounds__(256) void k_emb(const float* __restrict__ nf,
    const float* __restrict__ W, const float* __restrict__ b,
    unsigned short* __restrict__ node0)
{
    int idx = blockIdx.x*256 + threadIdx.x;
    if (idx >= NN*FF) return;
    int n = idx >> 6, c = idx & 63;
    float s = b[c];
    for (int k=0;k<OF;k++) s = fmaf(nf[(size_t)n*OF+k], W[k*FF+c], s);
    node0[idx] = f2bf(s);
}

// ---------------- slice reduce: st[lo..hi) = sum over NSLICE slices; clear slices ----------------
__global__ __launch_bounds__(256) void k_red(float* __restrict__ P,
    float* __restrict__ dst, int lo, int hi)
{
    for (int c = lo + threadIdx.x; c < hi; c += 256) {
        float s = 0.f;
        #pragma unroll 8
        for (int sl = 0; sl < NSLICE; ++sl) s += P[sl*PSTRIDE + c];
        dst[c] = s;
        #pragma unroll 8
        for (int sl = 0; sl < NSLICE; ++sl) P[sl*PSTRIDE + c] = 0.f;
    }
}

// ---------------- z staging into LDS (512 threads): issue-all-loads, then write ----------------
__device__ __forceinline__ void stage_z(unsigned short* __restrict__ Zl,
    const unsigned short* __restrict__ node_src, const unsigned short* __restrict__ edge_src,
    const int* __restrict__ eidx, int n0, int tid)
{
    const int gr0 = n0 * MM;
    const int r0 = tid >> 3, ch = tid & 7;
    const bool two = tid < 256;          // waves 0..3 also handle rows 64..95
    const int r1 = r0 + 64;
    const int e0 = eidx[gr0 + r0];
    const int e1 = two ? eidx[gr0 + r1] : 0;
    const int na0 = n0 + r0 / MM;
    const int na1 = n0 + r1 / MM;
    const uint4 z4 = make_uint4(0u,0u,0u,0u);
    uint4 s0  = *(const uint4*)(node_src + (size_t)na0*FF + ch*8);
    uint4 nb0 = *(const uint4*)(node_src + (size_t)e0*FF + ch*8);
    uint4 d0 = z4, s1 = z4, nb1 = z4, d1 = z4;
    if (ch < 6) d0 = *(const uint4*)(edge_src + (size_t)(gr0+r0)*ES + ch*8);
    if (two) {
        s1  = *(const uint4*)(node_src + (size_t)na1*FF + ch*8);
        nb1 = *(const uint4*)(node_src + (size_t)e1*FF + ch*8);
        if (ch < 6) d1 = *(const uint4*)(edge_src + (size_t)(gr0+r1)*ES + ch*8);
    }
    *(uint4*)(Zl + r0*KP + ch*8)        = s0;
    *(uint4*)(Zl + r0*KP + 64 + ch*8)   = nb0;
    *(uint4*)(Zl + r0*KP + 128 + ch*8)  = d0;   // ch 6,7 write zeros (K padding)
    if (two) {
        *(uint4*)(Zl + r1*KP + ch*8)       = s1;
        *(uint4*)(Zl + r1*KP + 64 + ch*8)  = nb1;
        *(uint4*)(Zl + r1*KP + 128 + ch*8) = d1;
    }
}

// ---------------- MFMA core: 6 M-tiles x 2 col tiles per wave (8 waves) ----------------
// wave w: h = w>>2 (0: cols 0..127 node-branch, 1: cols 128..255 edge-branch), sw = w&3.
// col(t) = h*128 + t*64 + sw*16 + li  ->  col-tile nt = h*8 + t*4 + sw
__device__ __forceinline__ void mfma_core(const unsigned short* __restrict__ Zl,
    const unsigned short* __restrict__ Wpk, int h, int sw, int lane, f32x4 (&acc)[MT][2])
{
    const int quad = lane >> 4, li = lane & 15;
    #pragma unroll
    for (int mt=0;mt<MT;mt++){
        acc[mt][0] = (f32x4){0.f,0.f,0.f,0.f};
        acc[mt][1] = (f32x4){0.f,0.f,0.f,0.f};
    }
    const int nt0 = h*8 + sw;
    #pragma unroll 2
    for (int ks=0; ks<KSTEPS; ++ks) {
        bf16x8 bfr0 = *(const bf16x8*)(Wpk + (((ks*16 + nt0    )*64 + lane) << 3));
        bf16x8 bfr1 = *(const bf16x8*)(Wpk + (((ks*16 + nt0 + 4)*64 + lane) << 3));
        bf16x8 afr[MT];
        #pragma unroll
        for (int mt=0;mt<MT;mt++)
            afr[mt] = *(const bf16x8*)(Zl + (mt*16+li)*KP + ks*32 + quad*8);
        #pragma unroll
        for (int mt=0;mt<MT;mt++){
            acc[mt][0] = __builtin_amdgcn_mfma_f32_16x16x32_bf16(afr[mt], bfr0, acc[mt][0], 0, 0, 0);
            acc[mt][1] = __builtin_amdgcn_mfma_f32_16x16x32_bf16(afr[mt], bfr1, acc[mt][1], 0, 0, 0);
        }
    }
}

// ---------------- stats epilogue (sliced accumulators: sumv at Ps[0], sumq at Ps[256]) ----------------
__device__ __forceinline__ void stats_epi(const f32x4 (&acc)[MT][2], int h, int sw, int lane,
    float* __restrict__ Ps)
{
    const int quad = lane>>4, li = lane&15;
    #pragma unroll
    for (int t=0;t<2;t++){
        float s=0.f, q=0.f;
        #pragma unroll
        for (int mt=0;mt<MT;mt++)
            #pragma unroll
            for (int r=0;r<4;r++){ float v = acc[mt][t][r]; s+=v; q = fmaf(v,v,q); }
        s += __shfl_xor(s,16); s += __shfl_xor(s,32);
        q += __shfl_xor(q,16); q += __shfl_xor(q,32);
        if (quad == 0) {
            int col = h*128 + t*64 + sw*16 + li;
            atomicAdd(&Ps[col], s);
            atomicAdd(&Ps[256+col], q);
        }
    }
}

// ---------------- GEMM + stats ----------------
__global__ __launch_bounds__(TPB,3) void k_stats(
    const unsigned short* __restrict__ node_src, const unsigned short* __restrict__ edge_src,
    const int* __restrict__ eidx, const unsigned short* __restrict__ Wpk,
    float* __restrict__ Pst)
{
    __shared__ unsigned short Zl[RPB*KP];
    const int tid = threadIdx.x, w = tid>>6, lane = tid&63;
    const int h = w>>2, sw = w&3;
    const int n0 = blockIdx.x * NPB;
    stage_z(Zl, node_src, edge_src, eidx, n0, tid);
    __syncthreads();
    f32x4 acc[MT][2];
    mfma_core(Zl, Wpk, h, sw, lane, acc);
    float* Ps = Pst + (size_t)(blockIdx.x & (NSLICE-1))*PSTRIDE;
    stats_epi(acc, h, sw, lane, Ps);
}

// ---------------- apply pass (recompute GEMM) ----------------
__global__ __launch_bounds__(TPB,3) void k_apply_re(
    const unsigned short* __restrict__ node_src, const unsigned short* __restrict__ edge_src,
    const int* __restrict__ eidx, const unsigned short* __restrict__ Wpk,
    const float* __restrict__ preS, const float* __restrict__ preQ,
    float* __restrict__ aggr, unsigned short* __restrict__ gbuf,
    float* __restrict__ Pst)
{
    __shared__ __align__(16) char smem[RPB*KP*2];   // Zl; gL [96][68] aliases after sync
    unsigned short* Zl = (unsigned short*)smem;
    float* gL = (float*)smem;
    const int tid = threadIdx.x, w = tid>>6, lane = tid&63;
    const int quad = lane>>4, li = lane&15;
    const int h = w>>2, sw = w&3;
    const int n0 = blockIdx.x * NPB;
    const int gr0 = n0 * MM;
    stage_z(Zl, node_src, edge_src, eidx, n0, tid);
    __syncthreads();
    f32x4 acc[MT][2];
    mfma_core(Zl, Wpk, h, sw, lane, acc);
    __syncthreads();                 // Zl dead -> gL may alias

    const int cg0 = sw*16 + li;
    float sc[2], bi[2];
    #pragma unroll
    for (int t=0;t<2;t++){
        int col = h*128 + t*64 + cg0;
        float mm = preS[col]*(1.f/(float)NM);
        float vv = preQ[col]*(1.f/(float)NM) - mm*mm;
        float is = rsqrtf(vv + 1e-5f);
        sc[t] = is; bi[t] = -mm*is;
    }
    float* Ps = Pst + (size_t)(blockIdx.x & (NSLICE-1))*PSTRIDE;

    if (h == 0) {
        // node gate: nf = col cg0, nc = col 64+cg0
        #pragma unroll
        for (int mt=0;mt<MT;mt++)
            #pragma unroll
            for (int r=0;r<4;r++){
                int row = mt*16 + quad*4 + r;
                float nf = fmaf(acc[mt][0][r], sc[0], bi[0]);
                float nc = fmaf(acc[mt][1][r], sc[1], bi[1]);
                gL[row*68 + cg0] = sigm(nf) * lrelu(nc);
            }
    } else {
        // edge gate: ef = col 128+cg0, ec = col 192+cg0
        const bool ce_ok = cg0 < EE;
        float pg = 0.f, pq = 0.f;
        #pragma unroll
        for (int mt=0;mt<MT;mt++)
            #pragma unroll
            for (int r=0;r<4;r++){
                int row = mt*16 + quad*4 + r;
                float ef = fmaf(acc[mt][0][r], sc[0], bi[0]);
                float ec = fmaf(acc[mt][1][r], sc[1], bi[1]);
                float gv = sigm(ef)*lrelu(ec);
                if (ce_ok) {
                    gbuf[(size_t)(gr0+row)*ES + cg0] = f2bf(gv);
                    pg += gv; pq = fmaf(gv,gv,pq);
                }
            }
        pg += __shfl_xor(pg,16); pg += __shfl_xor(pg,32);
        pq += __shfl_xor(pq,16); pq += __shfl_xor(pq,32);
        if (quad==0 && ce_ok){ atomicAdd(&Ps[640+cg0], pg); atomicAdd(&Ps[704+cg0], pq); }
    }
    __syncthreads();
    // aggr: wave w handles node n0+w (NPB == 8 waves), lane = col
    {
        float vsum = 0.f;
        #pragma unroll
        for (int jj=0;jj<MM;jj++) vsum += gL[(w*MM+jj)*68 + lane];
        aggr[(size_t)(n0+w)*64 + lane] = vsum;
        atomicAdd(&Ps[512+lane], vsum);
        atomicAdd(&Ps[576+lane], vsum*vsum);
    }
}

// ---------------- residual updates (scale/bias inline from raw sums) ----------------
__global__ __launch_bounds__(256) void k_upd_node(const unsigned short* __restrict__ cur,
    const float* __restrict__ aggr, const float* __restrict__ aS,
    const float* __restrict__ aQ, unsigned short* __restrict__ nxt)
{
    int idx = blockIdx.x*256 + threadIdx.x;
    if (idx >= NN*8) return;
    int n = idx >> 3, ch = idx & 7;
    int base = n*64 + ch*8;
    float4 a0 = *(const float4*)(aggr + base);
    float4 a1 = *(const float4*)(aggr + base + 4);
    uint4 cu = *(const uint4*)(cur + base);
    unsigned short cs[8]; *(uint4*)cs = cu;
    float av[8] = {a0.x,a0.y,a0.z,a0.w,a1.x,a1.y,a1.z,a1.w};
    unsigned short os[8];
    #pragma unroll
    for (int j=0;j<8;j++){
        int c = ch*8+j;
        float mm = aS[c]*(1.f/(float)NN);
        float vv = aQ[c]*(1.f/(float)NN) - mm*mm;
        float is = rsqrtf(vv + 1e-5f);
        float v = (av[j] - mm) * is;
        os[j] = f2bf(lrelu(b2f(cs[j]) + v));
    }
    *(uint4*)(nxt + base) = *(uint4*)os;
}

__global__ __launch_bounds__(256) void k_upd_edge(unsigned short* __restrict__ e,
    const unsigned short* __restrict__ g, const float* __restrict__ gS,
    const float* __restrict__ gQ)
{
    int idx = blockIdx.x*256 + threadIdx.x;
    if (idx >= NM*6) return;
    int gr = idx / 6, ch = idx - gr*6;
    size_t base = (size_t)gr*ES + ch*8;
    uint4 eu = *(const uint4*)(e + base);
    uint4 gu = *(const uint4*)(g + base);
    unsigned short es8[8], gs8[8], os[8];
    *(uint4*)es8 = eu; *(uint4*)gs8 = gu;
    #pragma unroll
    for (int j=0;j<8;j++){
        int c = ch*8+j;
        if (c < EE) {
            float mm = gS[c]*(1.f/(float)NM);
            float vv = gQ[c]*(1.f/(float)NM) - mm*mm;
            float is = rsqrtf(vv + 1e-5f);
            float v = (b2f(gs8[j]) - mm) * is;
            os[j] = f2bf(lrelu(b2f(es8[j]) + v));
        } else {
            os[j] = es8[j];
        }
    }
    *(uint4*)(e + base) = *(uint4*)os;
}

// ---------------- final heads (recompute GEMM) ----------------
__global__ __launch_bounds__(TPB,3) void k_final_re(
    const unsigned short* __restrict__ node_src, const unsigned short* __restrict__ edge_src,
    const int* __restrict__ eidx, const unsigned short* __restrict__ Wpk,
    const float* __restrict__ fS, const float* __restrict__ fQ,
    const float* __restrict__ distb, float* __restrict__ out)
{
    __shared__ __align__(16) char smem[RPB*KP*2];   // Zl; bufD/bufC alias after sync
    unsigned short* Zl = (unsigned short*)smem;
    float* bufD = (float*)smem;                     // [96][17]
    float* bufC = (float*)(smem + 8192);
    const int tid = threadIdx.x, w = tid>>6, lane = tid&63;
    const int quad = lane>>4, li = lane&15;
    const int h = w>>2, sw = w&3;
    const int n0 = blockIdx.x * NPB;
    const int gr0 = n0 * MM;
    stage_z(Zl, node_src, edge_src, eidx, n0, tid);
    __syncthreads();
    f32x4 acc[MT][2];
    mfma_core(Zl, Wpk, h, sw, lane, acc);
    __syncthreads();

    const int cg0 = sw*16 + li;
    float sc[2], bi[2];
    #pragma unroll
    for (int t=0;t<2;t++){
        int col = h*128 + t*64 + cg0;
        float mm = fS[col]*(1.f/(float)NM);
        float vv = fQ[col]*(1.f/(float)NM) - mm*mm;
        float is = rsqrtf(vv + 1e-5f);
        sc[t] = is; bi[t] = -mm*is;
    }
    const int liq = li >> 2;
    const bool wr = (li & 3) == 0;
    float* buf = (h == 0) ? bufD : bufC;
    #pragma unroll
    for (int mt=0;mt<MT;mt++)
        #pragma unroll
        for (int r=0;r<4;r++){
            int row = mt*16 + quad*4 + r;
            float v0 = fmaf(acc[mt][0][r], sc[0], bi[0]);
            float v1 = fmaf(acc[mt][1][r], sc[1], bi[1]);
            float p;
            if (h == 0) {
                float dv = distb[gr0 + row];
                p = softpl(v0 + dv) + softpl(v1 + dv);
            } else {
                p = softpl(v0) + softpl(v1);
            }
            p += __shfl_xor(p,1); p += __shfl_xor(p,2);
            if (wr) buf[row*17 + sw*4 + liq] = p;
        }
    __syncthreads();
    if (tid < 2*RPB) {
        int hh = tid >= RPB;
        int row = tid - (hh ? RPB : 0);
        const float* bsrc = hh ? bufC : bufD;
        float s = 0.f;
        #pragma unroll
        for (int t=0;t<16;t++) s += bsrc[row*17+t];
        size_t gr = gr0 + row;
        out[gr*2 + hh] = hh ? s * (1.f/128.f) * (1.f/(float)NN) : s * (1.f/128.f);
    }
}

// ---------------- launch ----------------
extern "C" void kernel_launch(void* const* d_in, const int* in_sizes, int n_in,
                              void* d_out, int out_size, void* d_ws, size_t ws_size,
                              hipStream_t stream)
{
    const float* node_fea = (const float*)d_in[0];
    const float* edge_in  = (const float*)d_in[1];
    const float* nbr_off  = (const float*)d_in[2];
    const float* apos     = (const float*)d_in[3];
    const float* cells    = (const float*)d_in[4];
    const int*   eidx     = (const int*)  d_in[5];
    const float* W_emb    = (const float*)d_in[6];
    const float* b_emb    = (const float*)d_in[7];
    const float* W_pn     = (const float*)d_in[8];
    const float* W_pe     = (const float*)d_in[10];
    const float* W_dist   = (const float*)d_in[12];
    const float* W_cst    = (const float*)d_in[14];
    float* out = (float*)d_out;
    char* ws = (char*)d_ws;

    size_t o = 0;
    auto alloc = [&](size_t bytes) { char* p = ws + o; o += (bytes + 255) & ~(size_t)255; return p; };
    unsigned short* node0 = (unsigned short*)alloc((size_t)NN*FF*2);
    unsigned short* node1 = (unsigned short*)alloc((size_t)NN*FF*2);
    unsigned short* ebuf  = (unsigned short*)alloc((size_t)NM*ES*2);
    unsigned short* gbuf  = (unsigned short*)alloc((size_t)NM*ES*2);
    float* aggr  = (float*)alloc((size_t)NN*FF*4);
    float* distb = (float*)alloc((size_t)NM*4);
    unsigned short* Wpk = (unsigned short*)alloc((size_t)4*49152*2);
    float* stats = (float*)alloc(4096*4);
    float* Pst   = (float*)alloc((size_t)NSLICE*PSTRIDE*4);   // sliced stats accumulators

    hipMemsetAsync(stats, 0, 4096*sizeof(float), stream);
    hipMemsetAsync(Pst, 0, (size_t)NSLICE*PSTRIDE*sizeof(float), stream);
    pack_w<<<(4*49152+255)/256, 256, 0, stream>>>(W_pn, W_pe, W_dist, W_cst, Wpk);
    k_dist <<<(NM+255)/256,     256, 0, stream>>>(nbr_off, apos, cells, eidx, distb);
    k_cvt  <<<(NM*ES+255)/256,  256, 0, stream>>>(edge_in, ebuf);
    k_emb  <<<(NN*FF+255)/256,  256, 0, stream>>>(node_fea, W_emb, b_emb, node0);

    const unsigned short* ncur = node0;

    for (int l=0;l<3;l++){
        float* st = stats + l*768;
        float* preS = st;       float* preQ = st+256;
        float* aSs  = st+512;   float* aQq  = st+576;
        float* gSs  = st+640;   float* gQq  = st+704;
        const unsigned short* Wl = Wpk + (size_t)l*49152;
        unsigned short* ndst = (l & 1) ? node0 : node1;

        k_stats  <<<NBLK,TPB,0,stream>>>(ncur, ebuf, eidx, Wl, Pst);
        k_red    <<<1,256,0,stream>>>(Pst, st, 0, 512);
        k_apply_re<<<NBLK,TPB,0,stream>>>(ncur, ebuf, eidx, Wl, preS, preQ,
                                          aggr, gbuf, Pst);
        k_red    <<<1,256,0,stream>>>(Pst, st, 512, 768);
        k_upd_node<<<(NN*8+255)/256,256,0,stream>>>(ncur, aggr, aSs, aQq, ndst);
        k_upd_edge<<<(NM*6+255)/256,256,0,stream>>>(ebuf, gbuf, gSs, gQq);
        ncur = ndst;
    }

    float* fSt = stats + 3*768;
    float* fS = fSt; float* fQ = fSt + 256;
    const unsigned short* Wf = Wpk + (size_t)3*49152;
    k_stats  <<<NBLK,TPB,0,stream>>>(ncur, ebuf, eidx, Wf, Pst);
    k_red    <<<1,256,0,stream>>>(Pst, fSt, 0, 512);
    k_final_re<<<NBLK,TPB,0,stream>>>(ncur, ebuf, eidx, Wf, fS, fQ, distb, out);
}